// Round 1
// baseline (352.516 us; speedup 1.0000x reference)
//
#include <hip/hip_runtime.h>
#include <hip/hip_bf16.h>

#define D_MODEL 1024
#define NHEADS  16
#define HDIM    64
#define SEQ     2048
#define BATCH   2
#define MROWS   (BATCH * SEQ)   // 4096

typedef __bf16 bf16x8 __attribute__((ext_vector_type(8)));
typedef float  f32x4  __attribute__((ext_vector_type(4)));

__device__ __forceinline__ unsigned short f2bf(float f) {
  unsigned u = __builtin_bit_cast(unsigned, f);
  return (unsigned short)((u + 0x7fffu + ((u >> 16) & 1u)) >> 16);
}

__device__ __forceinline__ f32x4 mfma_16x16x32(bf16x8 a, bf16x8 b, f32x4 c) {
  return __builtin_amdgcn_mfma_f32_16x16x32_bf16(a, b, c, 0, 0, 0);
}

__global__ void cvt_f32_bf16(const float* __restrict__ in,
                             unsigned short* __restrict__ out, int n4) {
  int i = blockIdx.x * blockDim.x + threadIdx.x;
  if (i >= n4) return;
  float4 v = reinterpret_cast<const float4*>(in)[i];
  ushort4 o;
  o.x = f2bf(v.x); o.y = f2bf(v.y); o.z = f2bf(v.z); o.w = f2bf(v.w);
  reinterpret_cast<ushort4*>(out)[i] = o;
}

// C = A[M,K] * Bt[N,K]^T + bias[N]
// MODE 0: out bf16 scatter to [B,H,S,64]   (Q, K)
// MODE 1: out bf16 scatter to [B,H,64,S]   (V transposed)
// MODE 2: out f32 row-major [M,N]          (final projection)
template <int MODE>
__global__ __launch_bounds__(256) void gemm_bt(
    const unsigned short* __restrict__ A,
    const unsigned short* __restrict__ Bt,
    const float* __restrict__ bias,
    void* __restrict__ outp, int M, int N, int K) {
  __shared__ unsigned short lA[128 * 32];
  __shared__ unsigned short lB[128 * 32];
  const int tid = threadIdx.x;
  const int m0 = blockIdx.y * 128, n0 = blockIdx.x * 128;
  const int lane = tid & 63, wid = tid >> 6;
  const int wr = wid >> 1, wc = wid & 1;
  const int fr = lane & 15, g = lane >> 4;
  const int lr = tid >> 2, lk = (tid & 3) * 8;

  const unsigned short* pa = A + (size_t)(m0 + lr) * K + lk;
  const unsigned short* pb = Bt + (size_t)(n0 + lr) * K + lk;

  f32x4 acc[4][4];
#pragma unroll
  for (int i = 0; i < 4; ++i)
#pragma unroll
    for (int j = 0; j < 4; ++j) acc[i][j] = (f32x4){0.f, 0.f, 0.f, 0.f};

  for (int kt = 0; kt < K; kt += 32) {
    uint4 a0 = *reinterpret_cast<const uint4*>(pa + kt);
    uint4 a1 = *reinterpret_cast<const uint4*>(pa + (size_t)64 * K + kt);
    uint4 b0 = *reinterpret_cast<const uint4*>(pb + kt);
    uint4 b1 = *reinterpret_cast<const uint4*>(pb + (size_t)64 * K + kt);
    __syncthreads();
    *reinterpret_cast<uint4*>(&lA[lr * 32 + lk]) = a0;
    *reinterpret_cast<uint4*>(&lA[(lr + 64) * 32 + lk]) = a1;
    *reinterpret_cast<uint4*>(&lB[lr * 32 + lk]) = b0;
    *reinterpret_cast<uint4*>(&lB[(lr + 64) * 32 + lk]) = b1;
    __syncthreads();
    bf16x8 af[4], bfv[4];
#pragma unroll
    for (int i = 0; i < 4; ++i)
      af[i] = *reinterpret_cast<const bf16x8*>(
          &lA[(wr * 64 + i * 16 + fr) * 32 + g * 8]);
#pragma unroll
    for (int j = 0; j < 4; ++j)
      bfv[j] = *reinterpret_cast<const bf16x8*>(
          &lB[(wc * 64 + j * 16 + fr) * 32 + g * 8]);
#pragma unroll
    for (int i = 0; i < 4; ++i)
#pragma unroll
      for (int j = 0; j < 4; ++j)
        acc[i][j] = mfma_16x16x32(af[i], bfv[j], acc[i][j]);
  }

#pragma unroll
  for (int i = 0; i < 4; ++i)
#pragma unroll
    for (int j = 0; j < 4; ++j)
#pragma unroll
      for (int r = 0; r < 4; ++r) {
        int m = m0 + wr * 64 + i * 16 + g * 4 + r;
        int n = n0 + wc * 64 + j * 16 + fr;
        float val = acc[i][j][r] + bias[n];
        if (MODE == 2) {
          reinterpret_cast<float*>(outp)[(size_t)m * N + n] = val;
        } else {
          int b = m >> 11, s = m & 2047;
          int hh = n >> 6, dh = n & 63;
          size_t idx;
          if (MODE == 0)
            idx = ((size_t)(b * NHEADS + hh) * SEQ + s) * HDIM + dh;
          else
            idx = ((size_t)(b * NHEADS + hh) * HDIM + dh) * SEQ + s;
          reinterpret_cast<unsigned short*>(outp)[idx] = f2bf(val);
        }
      }
}

// Flash-style causal attention. 1 wave per 16 query rows.
// Q,K: [B,H,S,64] bf16 ; Vt: [B,H,64,S] bf16 ; O: [B,S,1024] bf16
__global__ __launch_bounds__(64) void attn_fwd(
    const unsigned short* __restrict__ Q,
    const unsigned short* __restrict__ Km,
    const unsigned short* __restrict__ Vt,
    unsigned short* __restrict__ O) {
  const int lane = threadIdx.x;
  const int fr = lane & 15, g = lane >> 4;
  const int qt = blockIdx.x, h = blockIdx.y, b = blockIdx.z;
  const int bh = b * NHEADS + h;
  const int q0 = qt * 16;

  __shared__ unsigned short pl[16 * 32];

  const unsigned short* qb = Q + ((size_t)bh * SEQ + q0 + fr) * HDIM + g * 8;
  bf16x8 qa0 = *reinterpret_cast<const bf16x8*>(qb);
  bf16x8 qa1 = *reinterpret_cast<const bf16x8*>(qb + 32);

  const unsigned short* kb = Km + (size_t)bh * SEQ * HDIM;
  const unsigned short* vb = Vt + (size_t)bh * HDIM * SEQ;

  f32x4 oacc[4];
#pragma unroll
  for (int i = 0; i < 4; ++i) oacc[i] = (f32x4){0.f, 0.f, 0.f, 0.f};
  float mrow[4] = {-1e30f, -1e30f, -1e30f, -1e30f};
  float lrow[4] = {0.f, 0.f, 0.f, 0.f};

  const int nkt = (q0 + 16 + 31) >> 5;
  for (int kt = 0; kt < nkt; ++kt) {
    const int n0 = kt * 32;
    const unsigned short* kp0 = kb + (size_t)(n0 + fr) * HDIM + g * 8;
    const unsigned short* kp1 = kp0 + 16 * HDIM;
    bf16x8 k00 = *reinterpret_cast<const bf16x8*>(kp0);
    bf16x8 k01 = *reinterpret_cast<const bf16x8*>(kp0 + 32);
    bf16x8 k10 = *reinterpret_cast<const bf16x8*>(kp1);
    bf16x8 k11 = *reinterpret_cast<const bf16x8*>(kp1 + 32);
    f32x4 s0 = (f32x4){0.f, 0.f, 0.f, 0.f};
    f32x4 s1 = (f32x4){0.f, 0.f, 0.f, 0.f};
    s0 = mfma_16x16x32(qa0, k00, s0);
    s0 = mfma_16x16x32(qa1, k01, s0);
    s1 = mfma_16x16x32(qa0, k10, s1);
    s1 = mfma_16x16x32(qa1, k11, s1);

    float p0v[4], p1v[4];
#pragma unroll
    for (int r = 0; r < 4; ++r) {
      const int row = q0 + g * 4 + r;
      float sv0 = (n0 + fr <= row) ? s0[r] * 0.125f : -1e30f;
      float sv1 = (n0 + 16 + fr <= row) ? s1[r] * 0.125f : -1e30f;
      float tm = fmaxf(sv0, sv1);
#pragma unroll
      for (int msk = 1; msk < 16; msk <<= 1)
        tm = fmaxf(tm, __shfl_xor(tm, msk, 64));
      const float mn = fmaxf(mrow[r], tm);
      const float alpha = __expf(mrow[r] - mn);
      mrow[r] = mn;
      const float p0 = __expf(sv0 - mn);
      const float p1 = __expf(sv1 - mn);
      float ps = p0 + p1;
#pragma unroll
      for (int msk = 1; msk < 16; msk <<= 1)
        ps += __shfl_xor(ps, msk, 64);
      lrow[r] = lrow[r] * alpha + ps;
#pragma unroll
      for (int nf = 0; nf < 4; ++nf) oacc[nf][r] *= alpha;
      p0v[r] = p0;
      p1v[r] = p1;
    }
    __syncthreads();
#pragma unroll
    for (int r = 0; r < 4; ++r) {
      pl[(g * 4 + r) * 32 + fr] = f2bf(p0v[r]);
      pl[(g * 4 + r) * 32 + 16 + fr] = f2bf(p1v[r]);
    }
    __syncthreads();
    bf16x8 pa = *reinterpret_cast<const bf16x8*>(&pl[fr * 32 + g * 8]);
#pragma unroll
    for (int nf = 0; nf < 4; ++nf) {
      bf16x8 vf = *reinterpret_cast<const bf16x8*>(
          vb + (size_t)(nf * 16 + fr) * SEQ + n0 + g * 8);
      oacc[nf] = mfma_16x16x32(pa, vf, oacc[nf]);
    }
  }

#pragma unroll
  for (int r = 0; r < 4; ++r) {
    const float inv = 1.f / lrow[r];
    const size_t base = ((size_t)b * SEQ + q0 + g * 4 + r) * D_MODEL + h * HDIM;
#pragma unroll
    for (int nf = 0; nf < 4; ++nf)
      O[base + nf * 16 + fr] = f2bf(oacc[nf][r] * inv);
  }
}

extern "C" void kernel_launch(void* const* d_in, const int* in_sizes, int n_in,
                              void* d_out, int out_size, void* d_ws,
                              size_t ws_size, hipStream_t stream) {
  const float* x  = (const float*)d_in[0];
  const float* wq = (const float*)d_in[1];
  const float* bq = (const float*)d_in[2];
  const float* wk = (const float*)d_in[3];
  const float* bk = (const float*)d_in[4];
  const float* wv = (const float*)d_in[5];
  const float* bv = (const float*)d_in[6];
  const float* wo = (const float*)d_in[7];
  const float* bo = (const float*)d_in[8];
  float* out = (float*)d_out;

  char* w = (char*)d_ws;
  unsigned short* xb  = (unsigned short*)w; w += (size_t)MROWS * D_MODEL * 2;
  unsigned short* wqb = (unsigned short*)w; w += (size_t)D_MODEL * D_MODEL * 2;
  unsigned short* wkb = (unsigned short*)w; w += (size_t)D_MODEL * D_MODEL * 2;
  unsigned short* wvb = (unsigned short*)w; w += (size_t)D_MODEL * D_MODEL * 2;
  unsigned short* wob = (unsigned short*)w; w += (size_t)D_MODEL * D_MODEL * 2;
  unsigned short* Qb  = (unsigned short*)w; w += (size_t)BATCH * NHEADS * SEQ * HDIM * 2;
  unsigned short* Kb  = (unsigned short*)w; w += (size_t)BATCH * NHEADS * SEQ * HDIM * 2;
  unsigned short* Vtb = (unsigned short*)w; w += (size_t)BATCH * NHEADS * SEQ * HDIM * 2;
  unsigned short* Ob  = (unsigned short*)w; w += (size_t)MROWS * D_MODEL * 2;

  {
    int n4 = MROWS * D_MODEL / 4;
    cvt_f32_bf16<<<n4 / 256, 256, 0, stream>>>(x, xb, n4);
  }
  {
    int n4 = D_MODEL * D_MODEL / 4;
    cvt_f32_bf16<<<n4 / 256, 256, 0, stream>>>(wq, wqb, n4);
    cvt_f32_bf16<<<n4 / 256, 256, 0, stream>>>(wk, wkb, n4);
    cvt_f32_bf16<<<n4 / 256, 256, 0, stream>>>(wv, wvb, n4);
    cvt_f32_bf16<<<n4 / 256, 256, 0, stream>>>(wo, wob, n4);
  }

  dim3 gg(D_MODEL / 128, MROWS / 128);
  gemm_bt<0><<<gg, 256, 0, stream>>>(xb, wqb, bq, Qb, MROWS, D_MODEL, D_MODEL);
  gemm_bt<0><<<gg, 256, 0, stream>>>(xb, wkb, bk, Kb, MROWS, D_MODEL, D_MODEL);
  gemm_bt<1><<<gg, 256, 0, stream>>>(xb, wvb, bv, Vtb, MROWS, D_MODEL, D_MODEL);

  attn_fwd<<<dim3(SEQ / 16, NHEADS, BATCH), 64, 0, stream>>>(Qb, Kb, Vtb, Ob);

  gemm_bt<2><<<gg, 256, 0, stream>>>(Ob, wob, bo, out, MROWS, D_MODEL, D_MODEL);
}